// Round 1
// baseline (490.192 us; speedup 1.0000x reference)
//
#include <hip/hip_runtime.h>
#include <math.h>

#define NB   16
#define TSEQ 16384
#define DD   128
#define HH   256
constexpr float EPS = 1e-5f;

typedef _Float16 h8v __attribute__((ext_vector_type(8)));
typedef _Float16 h4v __attribute__((ext_vector_type(4)));
typedef float    f4v __attribute__((ext_vector_type(4)));

#define MFMA16(a, b, c) __builtin_amdgcn_mfma_f32_16x16x32_f16(a, b, c, 0, 0, 0)

constexpr int SX_S = 136;   // 272B rows: 2-way bank alias on b128 (free)
constexpr int SW_S = 136;
constexpr int K1_TM = 128;  // rows per tile
constexpr int K1_G  = 4;    // tiles per k1 block (split-K depth 512 t)
constexpr int K2_SPLIT = 32;  // partial S slots per batch = 512 blocks / 16 batches

__device__ __forceinline__ void atomicMaxFloat(float* addr, float val) {
    if (val >= 0.0f) atomicMax((int*)addr, __float_as_int(val));
    else             atomicMin((unsigned int*)addr, __float_as_uint(val));
}

// ---------------------------------------------------------------------------
// K0: cast Wv -> Wh[4], Wo*rms_w -> Wh[5]; init pooled.
// ---------------------------------------------------------------------------
__global__ __launch_bounds__(256) void k0_prep(
    const float* __restrict__ Wv, const float* __restrict__ Wo,
    const float* __restrict__ rmsw,
    _Float16* __restrict__ Wh, float* __restrict__ pooled)
{
    const int i = blockIdx.x * 256 + threadIdx.x;
    if (i < 2 * DD * DD) {
        const int mat = i >> 14;
        const int e   = i & (DD * DD - 1);
        float v = (mat == 0) ? Wv[e] : Wo[e] * rmsw[e & (DD - 1)];
        Wh[(4 + mat) * DD * DD + e] = (_Float16)v;
    }
    if (i < NB * DD) pooled[i] = -INFINITY;
}

// ---------------------------------------------------------------------------
// K0b: fold feature-map weights through the projections:
//   Wh[0]=fmq_w1@Wq  Wh[1]=fmq_w2@Wq  Wh[2]=fmk_w1@Wk  Wh[3]=fmk_w2@Wk
// A[o2][i] = sum_o fm[o2][o] * W[o][i].  32 blocks: 8 per matrix, 16 rows each.
// ---------------------------------------------------------------------------
__global__ __launch_bounds__(256) void k0_fold(
    const float* __restrict__ Wq, const float* __restrict__ Wk,
    const float* __restrict__ fq1, const float* __restrict__ fq2,
    const float* __restrict__ fk1, const float* __restrict__ fk2,
    _Float16* __restrict__ Wh)
{
    __shared__ _Float16 sW[DD * SX_S];   // base matrix [o][i]
    __shared__ _Float16 sF[16 * SX_S];   // fm rows     [o2r][o]
    const int mat  = blockIdx.x >> 3;    // 0..3
    const int rblk = blockIdx.x & 7;     // 16-row slice
    const float* fms[4] = {fq1, fq2, fk1, fk2};
    const float* base = (mat < 2) ? Wq : Wk;
    const float* fm   = fms[mat];
    const int tid = threadIdx.x;
    {   // stage base [128][128] fp32->fp16
        const int r = tid >> 1, c0 = (tid & 1) * 64;
        const float* src = base + r * DD + c0;
        _Float16* dst = sW + r * SX_S + c0;
#pragma unroll
        for (int i = 0; i < 16; ++i) {
            const float4 v = *(const float4*)(src + i * 4);
            h4v h; h[0] = (_Float16)v.x; h[1] = (_Float16)v.y;
                   h[2] = (_Float16)v.z; h[3] = (_Float16)v.w;
            *(h4v*)(dst + i * 4) = h;
        }
    }
    {   // stage fm rows [rblk*16 .. +16)
        const int r = tid >> 4, c0 = (tid & 15) * 8;
        const float* src = fm + (rblk * 16 + r) * DD + c0;
        _Float16* dst = sF + r * SX_S + c0;
#pragma unroll
        for (int i = 0; i < 2; ++i) {
            const float4 v = *(const float4*)(src + i * 4);
            h4v h; h[0] = (_Float16)v.x; h[1] = (_Float16)v.y;
                   h[2] = (_Float16)v.z; h[3] = (_Float16)v.w;
            *(h4v*)(dst + i * 4) = h;
        }
    }
    __syncthreads();
    const int o2r = tid >> 4, i0 = (tid & 15) * 8;
    float acc[8] = {0.f, 0.f, 0.f, 0.f, 0.f, 0.f, 0.f, 0.f};
    for (int o = 0; o < DD; ++o) {
        const float f = (float)sF[o2r * SX_S + o];
        const h8v w8 = *(const h8v*)(sW + o * SX_S + i0);
#pragma unroll
        for (int j = 0; j < 8; ++j) acc[j] = fmaf(f, (float)w8[j], acc[j]);
    }
    h8v hv;
#pragma unroll
    for (int j = 0; j < 8; ++j) hv[j] = (_Float16)acc[j];
    *(h8v*)(Wh + mat * DD * DD + (rblk * 16 + o2r) * DD + i0) = hv;
}

// ---------------------------------------------------------------------------
// K1-mega: per 128-t tile (G=4 tiles/block):
//   qf = (x@A1q^T + b1)*(x@A2q^T + b2)   -> global [t][d]
//   kf = (x@A1k^T + b1)*(x@A2k^T + b2)   -> LDS [d][t]
//   v  = x@Wv^T                          -> LDS [e][t]
//   accS[e][d] += sum_t v[t][e]*kf[t][d] (in-register split-K partial of S^T)
// No kfT/vT HBM traffic; one fp32 partial per block -> STf (same layout as
// old split-K, so k2r is unchanged). 5 barriers/tile (was 10 + K2's 16).
// 512 blocks x 512 thr; LDS 69632 B -> 2 blocks/CU; VGPR budget ~125/128.
// ---------------------------------------------------------------------------
__global__ __launch_bounds__(512, 4) void k1_mega(
    const float* __restrict__ x, const _Float16* __restrict__ Wh,
    const float* __restrict__ bq1, const float* __restrict__ bq2,
    const float* __restrict__ bk1, const float* __restrict__ bk2,
    _Float16* __restrict__ qf, float* __restrict__ STf)
{
    __shared__ _Float16 sX[K1_TM * SX_S];    // x tile [t][d], later v^T [e][t]
    __shared__ _Float16 sCT[K1_TM * SX_S];   // qf [t][d], later kf^T [d][t]

    const int tid = threadIdx.x;
    const int wv = tid >> 6;                 // 0..7 -> n-tile / S m-tile
    const int ln = tid & 63, lm = ln & 15, lq = ln >> 4;
    const long tb = (long)blockIdx.x * (K1_TM * K1_G);
    const int b = (int)(tb >> 14);

    const float vb1q = bq1[wv * 16 + lm], vb2q = bq2[wv * 16 + lm];
    const float vb1k = bk1[wv * 16 + lm], vb2k = bk2[wv * 16 + lm];

    auto loadW = [&](int mat, h8v* w) {
        const _Float16* p = Wh + mat * DD * DD + (wv * 16 + lm) * DD + lq * 8;
#pragma unroll
        for (int k0 = 0; k0 < 4; ++k0) w[k0] = *(const h8v*)(p + k0 * 32);
    };
    auto gemm = [&](const _Float16* sA, const h8v* w, f4v* acc) {
#pragma unroll
        for (int k0 = 0; k0 < 4; ++k0)
#pragma unroll
            for (int mt = 0; mt < 8; ++mt) {
                const h8v a = *(const h8v*)(sA + (mt * 16 + lm) * SX_S + k0 * 32 + lq * 8);
                acc[mt] = MFMA16(a, w[k0], acc[mt]);
            }
    };
    auto zero8 = [&](f4v* a) {
#pragma unroll
        for (int i = 0; i < 8; ++i) { a[i][0] = 0.f; a[i][1] = 0.f; a[i][2] = 0.f; a[i][3] = 0.f; }
    };

    f4v accS[8];
    zero8(accS);

    h8v w[4];
    f4v a1[8], a2[8];

#pragma unroll 1
    for (int g = 0; g < K1_G; ++g) {
        const long t0 = tb + (long)g * K1_TM;

        {   // stage x [128][128] fp32->fp16
            const int r = tid >> 2, c0 = (tid & 3) * 32;
            const float* src = x + (t0 + r) * DD + c0;
            _Float16* dst = sX + r * SX_S + c0;
#pragma unroll
            for (int i = 0; i < 8; ++i) {
                const float4 v = *(const float4*)(src + i * 4);
                h4v h; h[0] = (_Float16)v.x; h[1] = (_Float16)v.y;
                       h[2] = (_Float16)v.z; h[3] = (_Float16)v.w;
                *(h4v*)(dst + i * 4) = h;
            }
        }
        __syncthreads();                       // B1: sX ready (B5 guarded prev reads)

        // ---------------- q: two independent GEMMs off sX, hadamard
        loadW(0, w);
        zero8(a1); gemm(sX, w, a1);            // qa
        loadW(1, w);
        zero8(a2); gemm(sX, w, a2);            // qb
#pragma unroll
        for (int mt = 0; mt < 8; ++mt)
#pragma unroll
            for (int r = 0; r < 4; ++r)
                a1[mt][r] = (a1[mt][r] + vb1q) * (a2[mt][r] + vb2q);
#pragma unroll
        for (int mt = 0; mt < 8; ++mt)         // qf -> sCT [t][d]
#pragma unroll
            for (int r = 0; r < 4; ++r)
                sCT[(mt * 16 + lq * 4 + r) * SX_S + wv * 16 + lm] = (_Float16)a1[mt][r];
        __syncthreads();                       // B2: sCT = qf
        {   // qf -> global [t][d]
            const int r = tid >> 2, c0 = (tid & 3) * 32;
            const _Float16* s = sCT + r * SX_S + c0;
            _Float16* d = qf + (t0 + r) * DD + c0;
            *(h8v*)(d)      = *(const h8v*)(s);
            *(h8v*)(d + 8)  = *(const h8v*)(s + 8);
            *(h8v*)(d + 16) = *(const h8v*)(s + 16);
            *(h8v*)(d + 24) = *(const h8v*)(s + 24);
        }

        // ---------------- k: two independent GEMMs off sX, hadamard -> fp16 regs
        loadW(2, w);
        zero8(a1); gemm(sX, w, a1);            // ka
        loadW(3, w);
        zero8(a2); gemm(sX, w, a2);            // kb
        h4v kh[8];
#pragma unroll
        for (int mt = 0; mt < 8; ++mt)
#pragma unroll
            for (int r = 0; r < 4; ++r)
                kh[mt][r] = (_Float16)((a1[mt][r] + vb1k) * (a2[mt][r] + vb2k));

        // ---------------- v GEMM off sX -> fp16 regs
        loadW(4, w);
        zero8(a2); gemm(sX, w, a2);            // v
        h4v vh[8];
#pragma unroll
        for (int mt = 0; mt < 8; ++mt)
#pragma unroll
            for (int r = 0; r < 4; ++r) vh[mt][r] = (_Float16)a2[mt][r];
        __syncthreads();                       // B3: qf copy + all sX reads done

        // transpose into LDS: kf^T -> sCT [d][t], v^T -> sX [e][t]
#pragma unroll
        for (int mt = 0; mt < 8; ++mt)
            *(h4v*)(sCT + (wv * 16 + lm) * SX_S + mt * 16 + lq * 4) = kh[mt];
#pragma unroll
        for (int mt = 0; mt < 8; ++mt)
            *(h4v*)(sX + (wv * 16 + lm) * SX_S + mt * 16 + lq * 4) = vh[mt];
        __syncthreads();                       // B4: transposes ready

        // ---------------- S partial: accS[m=e][n=d] += v^T x kf^T over t(128)
#pragma unroll
        for (int k0 = 0; k0 < 4; ++k0) {
            const h8v av = *(const h8v*)(sX + (wv * 16 + lm) * SX_S + k0 * 32 + lq * 8);
#pragma unroll
            for (int nt = 0; nt < 8; ++nt) {
                const h8v bk = *(const h8v*)(sCT + (nt * 16 + lm) * SX_S + k0 * 32 + lq * 8);
                accS[nt] = MFMA16(av, bk, accS[nt]);
            }
        }
        __syncthreads();                       // B5: S reads done before next stage
    }

    // write split-K partial S^T [e][d] (same layout/slots as old K2)
    float* Pb = STf + (long)(b * K2_SPLIT + (blockIdx.x & (K2_SPLIT - 1))) * (DD * DD);
#pragma unroll
    for (int nt = 0; nt < 8; ++nt)
#pragma unroll
        for (int r = 0; r < 4; ++r)
            Pb[(wv * 16 + lq * 4 + r) * DD + nt * 16 + lm] = accS[nt][r];
}

// ---------------------------------------------------------------------------
// K2r: sum the 32 split-K partials per batch -> fp16 S^T. (unchanged)
// ---------------------------------------------------------------------------
__global__ __launch_bounds__(256) void k2r_reduce(const float* __restrict__ STf,
                                                  _Float16* __restrict__ STh)
{
    const int idx = blockIdx.x * 256 + threadIdx.x;
    const int b = idx >> 14, e = idx & (DD * DD - 1);
    const float* p = STf + (long)b * K2_SPLIT * (DD * DD) + e;
    float s0 = 0.f, s1 = 0.f, s2 = 0.f, s3 = 0.f;
#pragma unroll
    for (int j = 0; j < K2_SPLIT; j += 4) {
        s0 += p[(long)(j + 0) * (DD * DD)];
        s1 += p[(long)(j + 1) * (DD * DD)];
        s2 += p[(long)(j + 2) * (DD * DD)];
        s3 += p[(long)(j + 3) * (DD * DD)];
    }
    STh[idx] = (_Float16)((s0 + s1) + (s2 + s3));
}

// ---------------------------------------------------------------------------
// K3 (unchanged from R11; Wo' now lives at Wh[5]).
// ---------------------------------------------------------------------------
constexpr int K3_TC = 128;

__global__ __launch_bounds__(512, 4) void k3_ostage(const _Float16* __restrict__ qf,
                                                    const _Float16* __restrict__ STh,
                                                    const _Float16* __restrict__ WoH,
                                                    float* __restrict__ pooled)
{
    __shared__ _Float16 sA[DD * SW_S];
    __shared__ _Float16 sB[K3_TC * SX_S];
    __shared__ float sPart[2][DD];
    __shared__ float sRed[8][DD];
    const int tid = threadIdx.x;
    const int wv = tid >> 6, ln = tid & 63, lm = ln & 15, lq = ln >> 4;
    const int eg = wv & 1;
    const int tg = wv >> 1;
    const long t0 = (long)blockIdx.x * K3_TC;
    const int b = (int)(t0 >> 14);

    h8v wo[4];
    {
        const int r = tid >> 2, c0 = (tid & 3) * 32;
        const _Float16* src = WoH + r * DD + c0;
        wo[0] = *(const h8v*)(src);
        wo[1] = *(const h8v*)(src + 8);
        wo[2] = *(const h8v*)(src + 16);
        wo[3] = *(const h8v*)(src + 24);
    }
    {
        const int r = tid >> 2, c0 = (tid & 3) * 32;
        const _Float16* src = STh + (long)b * DD * DD + r * DD + c0;
        _Float16* dst = sA + r * SW_S + c0;
        *(h8v*)(dst)      = *(const h8v*)(src);
        *(h8v*)(dst + 8)  = *(const h8v*)(src + 8);
        *(h8v*)(dst + 16) = *(const h8v*)(src + 16);
        *(h8v*)(dst + 24) = *(const h8v*)(src + 24);
    }
    {
        const int r = tid >> 2, c0 = (tid & 3) * 32;
        const _Float16* src = qf + (t0 + r) * DD + c0;
        _Float16* dst = sB + r * SX_S + c0;
        *(h8v*)(dst)      = *(const h8v*)(src);
        *(h8v*)(dst + 8)  = *(const h8v*)(src + 8);
        *(h8v*)(dst + 16) = *(const h8v*)(src + 16);
        *(h8v*)(dst + 24) = *(const h8v*)(src + 24);
    }
    __syncthreads();                        // B1

    f4v acc[2][4];
#pragma unroll
    for (int i = 0; i < 2; ++i)
#pragma unroll
        for (int j = 0; j < 4; ++j) { acc[i][j][0]=0.f; acc[i][j][1]=0.f; acc[i][j][2]=0.f; acc[i][j][3]=0.f; }
#pragma unroll
    for (int k0 = 0; k0 < 4; ++k0) {
        const h8v bf0 = *(const h8v*)(sB + ((tg * 2 + 0) * 16 + lm) * SX_S + k0 * 32 + lq * 8);
        const h8v bf1 = *(const h8v*)(sB + ((tg * 2 + 1) * 16 + lm) * SX_S + k0 * 32 + lq * 8);
#pragma unroll
        for (int a = 0; a < 4; ++a) {
            const h8v af = *(const h8v*)(sA + ((eg * 4 + a) * 16 + lm) * SW_S + k0 * 32 + lq * 8);
            acc[0][a] = MFMA16(af, bf0, acc[0][a]);
            acc[1][a] = MFMA16(af, bf1, acc[1][a]);
        }
    }
    float ssp[2] = {0.f, 0.f};
#pragma unroll
    for (int bt = 0; bt < 2; ++bt)
#pragma unroll
        for (int a = 0; a < 4; ++a)
#pragma unroll
            for (int r = 0; r < 4; ++r) ssp[bt] += acc[bt][a][r] * acc[bt][a][r];
#pragma unroll
    for (int bt = 0; bt < 2; ++bt) {
        ssp[bt] += __shfl_xor(ssp[bt], 16, 64);
        ssp[bt] += __shfl_xor(ssp[bt], 32, 64);
    }
    if (lq == 0) {
        sPart[eg][tg * 32 + 0 * 16 + lm] = ssp[0];
        sPart[eg][tg * 32 + 1 * 16 + lm] = ssp[1];
    }
    __syncthreads();                        // B2
    float sc[2];
#pragma unroll
    for (int bt = 0; bt < 2; ++bt) {
        const int t = tg * 32 + bt * 16 + lm;
        sc[bt] = rsqrtf((sPart[0][t] + sPart[1][t]) * (1.0f / DD) + EPS);
    }
#pragma unroll
    for (int bt = 0; bt < 2; ++bt)
#pragma unroll
        for (int a = 0; a < 4; ++a) {
            h4v h;
#pragma unroll
            for (int r = 0; r < 4; ++r) h[r] = (_Float16)(acc[bt][a][r] * sc[bt]);
            *(h4v*)(sB + ((tg * 2 + bt) * 16 + lm) * SX_S + (eg * 4 + a) * 16 + lq * 4) = h;
        }
    {
        const int r = tid >> 2, c0 = (tid & 3) * 32;
        _Float16* dst = sA + r * SW_S + c0;
        *(h8v*)(dst)      = wo[0];
        *(h8v*)(dst + 8)  = wo[1];
        *(h8v*)(dst + 16) = wo[2];
        *(h8v*)(dst + 24) = wo[3];
    }
    __syncthreads();                        // B3

#pragma unroll
    for (int i = 0; i < 2; ++i)
#pragma unroll
        for (int j = 0; j < 4; ++j) { acc[i][j][0]=0.f; acc[i][j][1]=0.f; acc[i][j][2]=0.f; acc[i][j][3]=0.f; }
#pragma unroll
    for (int k0 = 0; k0 < 4; ++k0) {
        const h8v bf0 = *(const h8v*)(sB + ((tg * 2 + 0) * 16 + lm) * SX_S + k0 * 32 + lq * 8);
        const h8v bf1 = *(const h8v*)(sB + ((tg * 2 + 1) * 16 + lm) * SX_S + k0 * 32 + lq * 8);
#pragma unroll
        for (int a = 0; a < 4; ++a) {
            const h8v af = *(const h8v*)(sA + ((eg * 4 + a) * 16 + lm) * SW_S + k0 * 32 + lq * 8);
            acc[0][a] = MFMA16(af, bf0, acc[0][a]);
            acc[1][a] = MFMA16(af, bf1, acc[1][a]);
        }
    }
#pragma unroll
    for (int a = 0; a < 4; ++a)
#pragma unroll
        for (int r = 0; r < 4; ++r) {
            float m = fmaxf(acc[0][a][r], acc[1][a][r]);
            m = fmaxf(m, __shfl_xor(m, 1, 64));
            m = fmaxf(m, __shfl_xor(m, 2, 64));
            m = fmaxf(m, __shfl_xor(m, 4, 64));
            m = fmaxf(m, __shfl_xor(m, 8, 64));
            if (lm == 0) sRed[wv][(eg * 4 + a) * 16 + lq * 4 + r] = m;
        }
    __syncthreads();                        // B4
    if (tid < DD) {
        const int egc = tid >> 6;
        float m = sRed[0 * 2 + egc][tid];
#pragma unroll
        for (int g = 1; g < 4; ++g) m = fmaxf(m, sRed[g * 2 + egc][tid]);
        atomicMaxFloat(&pooled[b * DD + tid], m);
    }
}

// ---------------------------------------------------------------------------
// K4: out[b,h] = pooled[b] . Wp[h] + bp[h]
// ---------------------------------------------------------------------------
__global__ __launch_bounds__(HH) void k4_final(const float* __restrict__ pooled,
                                               const float* __restrict__ Wp,
                                               const float* __restrict__ bp,
                                               float* __restrict__ out)
{
    const int b = blockIdx.x;
    const int h = threadIdx.x;
    __shared__ float sp[DD];
    if (h < DD) sp[h] = pooled[b * DD + h];
    __syncthreads();
    float acc = bp[h];
#pragma unroll 8
    for (int d = 0; d < DD; ++d) acc = fmaf(sp[d], Wp[(long)h * DD + d], acc);
    out[b * HH + h] = acc;
}

// ---------------------------------------------------------------------------
extern "C" void kernel_launch(void* const* d_in, const int* in_sizes, int n_in,
                              void* d_out, int out_size, void* d_ws, size_t ws_size,
                              hipStream_t stream)
{
    const float* x      = (const float*)d_in[0];
    const float* Wq     = (const float*)d_in[1];
    const float* Wk     = (const float*)d_in[2];
    const float* Wv     = (const float*)d_in[3];
    const float* fmq_w1 = (const float*)d_in[4];
    const float* fmq_b1 = (const float*)d_in[5];
    const float* fmq_w2 = (const float*)d_in[6];
    const float* fmq_b2 = (const float*)d_in[7];
    const float* fmk_w1 = (const float*)d_in[8];
    const float* fmk_b1 = (const float*)d_in[9];
    const float* fmk_w2 = (const float*)d_in[10];
    const float* fmk_b2 = (const float*)d_in[11];
    const float* rms_w  = (const float*)d_in[12];
    const float* Wo     = (const float*)d_in[13];
    const float* Wp     = (const float*)d_in[14];
    const float* bp     = (const float*)d_in[15];
    float* out = (float*)d_out;

    const long nTD = (long)NB * TSEQ * DD;
    _Float16* qf  = (_Float16*)d_ws;
    _Float16* Wh  = qf + nTD;                    // 6 fp16 matrices
    float* STf    = (float*)(Wh + 6 * DD * DD);
    _Float16* STh = (_Float16*)(STf + (long)NB * K2_SPLIT * DD * DD);
    float* pooled = (float*)(STh + NB * DD * DD);

    k0_prep<<<(2 * DD * DD) / 256, 256, 0, stream>>>(Wv, Wo, rms_w, Wh, pooled);
    k0_fold<<<32, 256, 0, stream>>>(Wq, Wk, fmq_w1, fmq_w2, fmk_w1, fmk_w2, Wh);
    k1_mega<<<(NB * TSEQ) / (K1_TM * K1_G), 512, 0, stream>>>(
        x, Wh, fmq_b1, fmq_b2, fmk_b1, fmk_b2, qf, STf);
    k2r_reduce<<<(NB * DD * DD) / 256, 256, 0, stream>>>(STf, STh);
    k3_ostage<<<(NB * TSEQ) / K3_TC, 512, 0, stream>>>(qf, STh, Wh + 5 * DD * DD, pooled);
    k4_final<<<NB, HH, 0, stream>>>(pooled, Wp, bp, out);
}

// Round 2
// 471.965 us; speedup vs baseline: 1.0386x; 1.0386x over previous
//
#include <hip/hip_runtime.h>
#include <math.h>

#define NB   16
#define TSEQ 16384
#define DD   128
#define HH   256
constexpr float EPS = 1e-5f;

typedef _Float16 h8v __attribute__((ext_vector_type(8)));
typedef _Float16 h4v __attribute__((ext_vector_type(4)));
typedef float    f4v __attribute__((ext_vector_type(4)));

#define MFMA16(a, b, c) __builtin_amdgcn_mfma_f32_16x16x32_f16(a, b, c, 0, 0, 0)

constexpr int SX_S = 136;   // 272B rows: 2-way bank alias on b128 (free)
constexpr int SW_S = 136;
constexpr int K1_TM = 128;  // rows per tile
constexpr int K1_G  = 4;    // tiles per k1 block (split-K depth 512 t)
constexpr int K2_SPLIT = 32;  // partial S slots per batch = 512 blocks / 16 batches

__device__ __forceinline__ void atomicMaxFloat(float* addr, float val) {
    if (val >= 0.0f) atomicMax((int*)addr, __float_as_int(val));
    else             atomicMin((unsigned int*)addr, __float_as_uint(val));
}

// ---------------------------------------------------------------------------
// K0: cast Wv -> Wh[4], Wo*rms_w -> Wh[5]; init pooled.
// ---------------------------------------------------------------------------
__global__ __launch_bounds__(256) void k0_prep(
    const float* __restrict__ Wv, const float* __restrict__ Wo,
    const float* __restrict__ rmsw,
    _Float16* __restrict__ Wh, float* __restrict__ pooled)
{
    const int i = blockIdx.x * 256 + threadIdx.x;
    if (i < 2 * DD * DD) {
        const int mat = i >> 14;
        const int e   = i & (DD * DD - 1);
        float v = (mat == 0) ? Wv[e] : Wo[e] * rmsw[e & (DD - 1)];
        Wh[(4 + mat) * DD * DD + e] = (_Float16)v;
    }
    if (i < NB * DD) pooled[i] = -INFINITY;
}

// ---------------------------------------------------------------------------
// K0b: fold feature-map weights through the projections:
//   Wh[0]=fmq_w1@Wq  Wh[1]=fmq_w2@Wq  Wh[2]=fmk_w1@Wk  Wh[3]=fmk_w2@Wk
// ---------------------------------------------------------------------------
__global__ __launch_bounds__(256) void k0_fold(
    const float* __restrict__ Wq, const float* __restrict__ Wk,
    const float* __restrict__ fq1, const float* __restrict__ fq2,
    const float* __restrict__ fk1, const float* __restrict__ fk2,
    _Float16* __restrict__ Wh)
{
    __shared__ _Float16 sW[DD * SX_S];   // base matrix [o][i]
    __shared__ _Float16 sF[16 * SX_S];   // fm rows     [o2r][o]
    const int mat  = blockIdx.x >> 3;    // 0..3
    const int rblk = blockIdx.x & 7;     // 16-row slice
    const float* fms[4] = {fq1, fq2, fk1, fk2};
    const float* base = (mat < 2) ? Wq : Wk;
    const float* fm   = fms[mat];
    const int tid = threadIdx.x;
    {   // stage base [128][128] fp32->fp16
        const int r = tid >> 1, c0 = (tid & 1) * 64;
        const float* src = base + r * DD + c0;
        _Float16* dst = sW + r * SX_S + c0;
#pragma unroll
        for (int i = 0; i < 16; ++i) {
            const float4 v = *(const float4*)(src + i * 4);
            h4v h; h[0] = (_Float16)v.x; h[1] = (_Float16)v.y;
                   h[2] = (_Float16)v.z; h[3] = (_Float16)v.w;
            *(h4v*)(dst + i * 4) = h;
        }
    }
    {   // stage fm rows [rblk*16 .. +16)
        const int r = tid >> 4, c0 = (tid & 15) * 8;
        const float* src = fm + (rblk * 16 + r) * DD + c0;
        _Float16* dst = sF + r * SX_S + c0;
#pragma unroll
        for (int i = 0; i < 2; ++i) {
            const float4 v = *(const float4*)(src + i * 4);
            h4v h; h[0] = (_Float16)v.x; h[1] = (_Float16)v.y;
                   h[2] = (_Float16)v.z; h[3] = (_Float16)v.w;
            *(h4v*)(dst + i * 4) = h;
        }
    }
    __syncthreads();
    const int o2r = tid >> 4, i0 = (tid & 15) * 8;
    float acc[8] = {0.f, 0.f, 0.f, 0.f, 0.f, 0.f, 0.f, 0.f};
    for (int o = 0; o < DD; ++o) {
        const float f = (float)sF[o2r * SX_S + o];
        const h8v w8 = *(const h8v*)(sW + o * SX_S + i0);
#pragma unroll
        for (int j = 0; j < 8; ++j) acc[j] = fmaf(f, (float)w8[j], acc[j]);
    }
    h8v hv;
#pragma unroll
    for (int j = 0; j < 8; ++j) hv[j] = (_Float16)acc[j];
    *(h8v*)(Wh + mat * DD * DD + (rblk * 16 + o2r) * DD + i0) = hv;
}

// ---------------------------------------------------------------------------
// K1-mega v2 (spill-free restructure of R0's fusion):
// per 128-t tile (G=4 tiles/block):
//   qf = (x@A1q^T+b1)*(x@A2q^T+b2) -> global [t][d]
//   kf = (x@A1k^T+b1)*(x@A2k^T+b2) -> LDS [d][t] (written straight from a1)
//   v  = x@Wv^T                    -> LDS [e][t] (written straight from a1)
//   accS[e][d] += v^T x kf^T       (in-register split-K partial of S^T)
// Register discipline: ONE fp32 accumulator set a1[8] reused for all GEMMs;
// second feature-map GEMM is computed per-fragment (t, 4 regs) and fused
// into a1 immediately. Peak acc regs = accS(32)+a1(32)+w(16)+t(~8) ~ 108.
// 6 barriers/tile. 512 blocks x 512 thr, all resident (2 blocks/CU).
// ---------------------------------------------------------------------------
__global__ __launch_bounds__(512, 4) void k1_mega(
    const float* __restrict__ x, const _Float16* __restrict__ Wh,
    const float* __restrict__ bq1, const float* __restrict__ bq2,
    const float* __restrict__ bk1, const float* __restrict__ bk2,
    _Float16* __restrict__ qf, float* __restrict__ STf)
{
    __shared__ _Float16 sX[K1_TM * SX_S];    // x tile [t][d], later v^T [e][t]
    __shared__ _Float16 sCT[K1_TM * SX_S];   // qf [t][d], later kf^T [d][t]

    const int tid = threadIdx.x;
    const int wv = tid >> 6;                 // 0..7
    const int ln = tid & 63, lm = ln & 15, lq = ln >> 4;
    const long tb = (long)blockIdx.x * (K1_TM * K1_G);
    const int b = (int)(tb >> 14);

    const float vb1q = bq1[wv * 16 + lm], vb2q = bq2[wv * 16 + lm];
    const float vb1k = bk1[wv * 16 + lm], vb2k = bk2[wv * 16 + lm];

    auto loadW = [&](int mat, h8v* w) {
        const _Float16* p = Wh + mat * DD * DD + (wv * 16 + lm) * DD + lq * 8;
#pragma unroll
        for (int k0 = 0; k0 < 4; ++k0) w[k0] = *(const h8v*)(p + k0 * 32);
    };
    auto gemm = [&](const _Float16* sA, const h8v* w, f4v* acc) {
#pragma unroll
        for (int k0 = 0; k0 < 4; ++k0)
#pragma unroll
            for (int mt = 0; mt < 8; ++mt) {
                const h8v a = *(const h8v*)(sA + (mt * 16 + lm) * SX_S + k0 * 32 + lq * 8);
                acc[mt] = MFMA16(a, w[k0], acc[mt]);
            }
    };
    // second GEMM fused: per-mt fragment t, hadamard into a immediately
    auto fusedHad = [&](const _Float16* sA, const h8v* w, f4v* a,
                        float b1, float b2) {
#pragma unroll
        for (int mt = 0; mt < 8; ++mt) {
            f4v t; t[0] = 0.f; t[1] = 0.f; t[2] = 0.f; t[3] = 0.f;
#pragma unroll
            for (int k0 = 0; k0 < 4; ++k0) {
                const h8v av = *(const h8v*)(sA + (mt * 16 + lm) * SX_S + k0 * 32 + lq * 8);
                t = MFMA16(av, w[k0], t);
            }
#pragma unroll
            for (int r = 0; r < 4; ++r)
                a[mt][r] = (a[mt][r] + b1) * (t[r] + b2);
        }
    };
    auto zero8 = [&](f4v* a) {
#pragma unroll
        for (int i = 0; i < 8; ++i) { a[i][0] = 0.f; a[i][1] = 0.f; a[i][2] = 0.f; a[i][3] = 0.f; }
    };
    auto cToC = [&](const f4v* a) {          // a -> sCT [t][d]
#pragma unroll
        for (int mt = 0; mt < 8; ++mt)
#pragma unroll
            for (int r = 0; r < 4; ++r)
                sCT[(mt * 16 + lq * 4 + r) * SX_S + wv * 16 + lm] = (_Float16)a[mt][r];
    };
    auto cToT = [&](const f4v* a, _Float16* dst) {  // a -> dst [d][t]
#pragma unroll
        for (int mt = 0; mt < 8; ++mt) {
            h4v h;
#pragma unroll
            for (int r = 0; r < 4; ++r) h[r] = (_Float16)a[mt][r];
            *(h4v*)(dst + (wv * 16 + lm) * SX_S + mt * 16 + lq * 4) = h;
        }
    };

    f4v accS[8];
    zero8(accS);

    h8v w[4];
    f4v a1[8];

#pragma unroll 1
    for (int g = 0; g < K1_G; ++g) {
        const long t0 = tb + (long)g * K1_TM;

        {   // stage x [128][128] fp32->fp16
            const int r = tid >> 2, c0 = (tid & 3) * 32;
            const float* src = x + (t0 + r) * DD + c0;
            _Float16* dst = sX + r * SX_S + c0;
#pragma unroll
            for (int i = 0; i < 8; ++i) {
                const float4 v = *(const float4*)(src + i * 4);
                h4v h; h[0] = (_Float16)v.x; h[1] = (_Float16)v.y;
                       h[2] = (_Float16)v.z; h[3] = (_Float16)v.w;
                *(h4v*)(dst + i * 4) = h;
            }
        }
        __syncthreads();                       // B1: sX ready (B6 guarded prev reads)

        // ---------------- q
        loadW(0, w);
        zero8(a1); gemm(sX, w, a1);            // qa
        loadW(1, w);
        fusedHad(sX, w, a1, vb1q, vb2q);       // a1 = (qa+b1)*(qb+b2)
        cToC(a1);                              // qf -> sCT [t][d]
        __syncthreads();                       // B2: sCT = qf
        {   // qf -> global [t][d]
            const int r = tid >> 2, c0 = (tid & 3) * 32;
            const _Float16* s = sCT + r * SX_S + c0;
            _Float16* d = qf + (t0 + r) * DD + c0;
            *(h8v*)(d)      = *(const h8v*)(s);
            *(h8v*)(d + 8)  = *(const h8v*)(s + 8);
            *(h8v*)(d + 16) = *(const h8v*)(s + 16);
            *(h8v*)(d + 24) = *(const h8v*)(s + 24);
        }

        // ---------------- k (reads sX only; overlaps qf store latency)
        loadW(2, w);
        zero8(a1); gemm(sX, w, a1);            // ka
        loadW(3, w);
        fusedHad(sX, w, a1, vb1k, vb2k);       // a1 = kf (fp32)
        __syncthreads();                       // B3: qf copy reads of sCT done
        cToT(a1, sCT);                         // kf^T -> sCT [d][t]

        // ---------------- v (reads sX; sCT writes in flight, no conflict)
        loadW(4, w);
        zero8(a1); gemm(sX, w, a1);            // v
        __syncthreads();                       // B4: all sX reads + kf^T writes done
        cToT(a1, sX);                          // v^T -> sX [e][t]
        __syncthreads();                       // B5: transposes ready

        // ---------------- S partial: accS[m=e][n=d] += v^T x kf^T over t(128)
#pragma unroll
        for (int k0 = 0; k0 < 4; ++k0) {
            const h8v av = *(const h8v*)(sX + (wv * 16 + lm) * SX_S + k0 * 32 + lq * 8);
#pragma unroll
            for (int nt = 0; nt < 8; ++nt) {
                const h8v bk = *(const h8v*)(sCT + (nt * 16 + lm) * SX_S + k0 * 32 + lq * 8);
                accS[nt] = MFMA16(av, bk, accS[nt]);
            }
        }
        __syncthreads();                       // B6: S reads done before next stage
    }

    // write split-K partial S^T [e][d] (same layout/slots as old K2)
    float* Pb = STf + (long)(b * K2_SPLIT + (blockIdx.x & (K2_SPLIT - 1))) * (DD * DD);
#pragma unroll
    for (int nt = 0; nt < 8; ++nt)
#pragma unroll
        for (int r = 0; r < 4; ++r)
            Pb[(wv * 16 + lq * 4 + r) * DD + nt * 16 + lm] = accS[nt][r];
}

// ---------------------------------------------------------------------------
// K2r: sum the 32 split-K partials per batch -> fp16 S^T. (unchanged)
// ---------------------------------------------------------------------------
__global__ __launch_bounds__(256) void k2r_reduce(const float* __restrict__ STf,
                                                  _Float16* __restrict__ STh)
{
    const int idx = blockIdx.x * 256 + threadIdx.x;
    const int b = idx >> 14, e = idx & (DD * DD - 1);
    const float* p = STf + (long)b * K2_SPLIT * (DD * DD) + e;
    float s0 = 0.f, s1 = 0.f, s2 = 0.f, s3 = 0.f;
#pragma unroll
    for (int j = 0; j < K2_SPLIT; j += 4) {
        s0 += p[(long)(j + 0) * (DD * DD)];
        s1 += p[(long)(j + 1) * (DD * DD)];
        s2 += p[(long)(j + 2) * (DD * DD)];
        s3 += p[(long)(j + 3) * (DD * DD)];
    }
    STh[idx] = (_Float16)((s0 + s1) + (s2 + s3));
}

// ---------------------------------------------------------------------------
// K3 (unchanged; Wo' lives at Wh[5]).
// ---------------------------------------------------------------------------
constexpr int K3_TC = 128;

__global__ __launch_bounds__(512, 4) void k3_ostage(const _Float16* __restrict__ qf,
                                                    const _Float16* __restrict__ STh,
                                                    const _Float16* __restrict__ WoH,
                                                    float* __restrict__ pooled)
{
    __shared__ _Float16 sA[DD * SW_S];
    __shared__ _Float16 sB[K3_TC * SX_S];
    __shared__ float sPart[2][DD];
    __shared__ float sRed[8][DD];
    const int tid = threadIdx.x;
    const int wv = tid >> 6, ln = tid & 63, lm = ln & 15, lq = ln >> 4;
    const int eg = wv & 1;
    const int tg = wv >> 1;
    const long t0 = (long)blockIdx.x * K3_TC;
    const int b = (int)(t0 >> 14);

    h8v wo[4];
    {
        const int r = tid >> 2, c0 = (tid & 3) * 32;
        const _Float16* src = WoH + r * DD + c0;
        wo[0] = *(const h8v*)(src);
        wo[1] = *(const h8v*)(src + 8);
        wo[2] = *(const h8v*)(src + 16);
        wo[3] = *(const h8v*)(src + 24);
    }
    {
        const int r = tid >> 2, c0 = (tid & 3) * 32;
        const _Float16* src = STh + (long)b * DD * DD + r * DD + c0;
        _Float16* dst = sA + r * SW_S + c0;
        *(h8v*)(dst)      = *(const h8v*)(src);
        *(h8v*)(dst + 8)  = *(const h8v*)(src + 8);
        *(h8v*)(dst + 16) = *(const h8v*)(src + 16);
        *(h8v*)(dst + 24) = *(const h8v*)(src + 24);
    }
    {
        const int r = tid >> 2, c0 = (tid & 3) * 32;
        const _Float16* src = qf + (t0 + r) * DD + c0;
        _Float16* dst = sB + r * SX_S + c0;
        *(h8v*)(dst)      = *(const h8v*)(src);
        *(h8v*)(dst + 8)  = *(const h8v*)(src + 8);
        *(h8v*)(dst + 16) = *(const h8v*)(src + 16);
        *(h8v*)(dst + 24) = *(const h8v*)(src + 24);
    }
    __syncthreads();                        // B1

    f4v acc[2][4];
#pragma unroll
    for (int i = 0; i < 2; ++i)
#pragma unroll
        for (int j = 0; j < 4; ++j) { acc[i][j][0]=0.f; acc[i][j][1]=0.f; acc[i][j][2]=0.f; acc[i][j][3]=0.f; }
#pragma unroll
    for (int k0 = 0; k0 < 4; ++k0) {
        const h8v bf0 = *(const h8v*)(sB + ((tg * 2 + 0) * 16 + lm) * SX_S + k0 * 32 + lq * 8);
        const h8v bf1 = *(const h8v*)(sB + ((tg * 2 + 1) * 16 + lm) * SX_S + k0 * 32 + lq * 8);
#pragma unroll
        for (int a = 0; a < 4; ++a) {
            const h8v af = *(const h8v*)(sA + ((eg * 4 + a) * 16 + lm) * SW_S + k0 * 32 + lq * 8);
            acc[0][a] = MFMA16(af, bf0, acc[0][a]);
            acc[1][a] = MFMA16(af, bf1, acc[1][a]);
        }
    }
    float ssp[2] = {0.f, 0.f};
#pragma unroll
    for (int bt = 0; bt < 2; ++bt)
#pragma unroll
        for (int a = 0; a < 4; ++a)
#pragma unroll
            for (int r = 0; r < 4; ++r) ssp[bt] += acc[bt][a][r] * acc[bt][a][r];
#pragma unroll
    for (int bt = 0; bt < 2; ++bt) {
        ssp[bt] += __shfl_xor(ssp[bt], 16, 64);
        ssp[bt] += __shfl_xor(ssp[bt], 32, 64);
    }
    if (lq == 0) {
        sPart[eg][tg * 32 + 0 * 16 + lm] = ssp[0];
        sPart[eg][tg * 32 + 1 * 16 + lm] = ssp[1];
    }
    __syncthreads();                        // B2
    float sc[2];
#pragma unroll
    for (int bt = 0; bt < 2; ++bt) {
        const int t = tg * 32 + bt * 16 + lm;
        sc[bt] = rsqrtf((sPart[0][t] + sPart[1][t]) * (1.0f / DD) + EPS);
    }
#pragma unroll
    for (int bt = 0; bt < 2; ++bt)
#pragma unroll
        for (int a = 0; a < 4; ++a) {
            h4v h;
#pragma unroll
            for (int r = 0; r < 4; ++r) h[r] = (_Float16)(acc[bt][a][r] * sc[bt]);
            *(h4v*)(sB + ((tg * 2 + bt) * 16 + lm) * SX_S + (eg * 4 + a) * 16 + lq * 4) = h;
        }
    {
        const int r = tid >> 2, c0 = (tid & 3) * 32;
        _Float16* dst = sA + r * SW_S + c0;
        *(h8v*)(dst)      = wo[0];
        *(h8v*)(dst + 8)  = wo[1];
        *(h8v*)(dst + 16) = wo[2];
        *(h8v*)(dst + 24) = wo[3];
    }
    __syncthreads();                        // B3

#pragma unroll
    for (int i = 0; i < 2; ++i)
#pragma unroll
        for (int j = 0; j < 4; ++j) { acc[i][j][0]=0.f; acc[i][j][1]=0.f; acc[i][j][2]=0.f; acc[i][j][3]=0.f; }
#pragma unroll
    for (int k0 = 0; k0 < 4; ++k0) {
        const h8v bf0 = *(const h8v*)(sB + ((tg * 2 + 0) * 16 + lm) * SX_S + k0 * 32 + lq * 8);
        const h8v bf1 = *(const h8v*)(sB + ((tg * 2 + 1) * 16 + lm) * SX_S + k0 * 32 + lq * 8);
#pragma unroll
        for (int a = 0; a < 4; ++a) {
            const h8v af = *(const h8v*)(sA + ((eg * 4 + a) * 16 + lm) * SW_S + k0 * 32 + lq * 8);
            acc[0][a] = MFMA16(af, bf0, acc[0][a]);
            acc[1][a] = MFMA16(af, bf1, acc[1][a]);
        }
    }
#pragma unroll
    for (int a = 0; a < 4; ++a)
#pragma unroll
        for (int r = 0; r < 4; ++r) {
            float m = fmaxf(acc[0][a][r], acc[1][a][r]);
            m = fmaxf(m, __shfl_xor(m, 1, 64));
            m = fmaxf(m, __shfl_xor(m, 2, 64));
            m = fmaxf(m, __shfl_xor(m, 4, 64));
            m = fmaxf(m, __shfl_xor(m, 8, 64));
            if (lm == 0) sRed[wv][(eg * 4 + a) * 16 + lq * 4 + r] = m;
        }
    __syncthreads();                        // B4
    if (tid < DD) {
        const int egc = tid >> 6;
        float m = sRed[0 * 2 + egc][tid];
#pragma unroll
        for (int g = 1; g < 4; ++g) m = fmaxf(m, sRed[g * 2 + egc][tid]);
        atomicMaxFloat(&pooled[b * DD + tid], m);
    }
}

// ---------------------------------------------------------------------------
// K4: out[b,h] = pooled[b] . Wp[h] + bp[h]
// ---------------------------------------------------------------------------
__global__ __launch_bounds__(HH) void k4_final(const float* __restrict__ pooled,
                                               const float* __restrict__ Wp,
                                               const float* __restrict__ bp,
                                               float* __restrict__ out)
{
    const int b = blockIdx.x;
    const int h = threadIdx.x;
    __shared__ float sp[DD];
    if (h < DD) sp[h] = pooled[b * DD + h];
    __syncthreads();
    float acc = bp[h];
#pragma unroll 8
    for (int d = 0; d < DD; ++d) acc = fmaf(sp[d], Wp[(long)h * DD + d], acc);
    out[b * HH + h] = acc;
}

// ---------------------------------------------------------------------------
extern "C" void kernel_launch(void* const* d_in, const int* in_sizes, int n_in,
                              void* d_out, int out_size, void* d_ws, size_t ws_size,
                              hipStream_t stream)
{
    const float* x      = (const float*)d_in[0];
    const float* Wq     = (const float*)d_in[1];
    const float* Wk     = (const float*)d_in[2];
    const float* Wv     = (const float*)d_in[3];
    const float* fmq_w1 = (const float*)d_in[4];
    const float* fmq_b1 = (const float*)d_in[5];
    const float* fmq_w2 = (const float*)d_in[6];
    const float* fmq_b2 = (const float*)d_in[7];
    const float* fmk_w1 = (const float*)d_in[8];
    const float* fmk_b1 = (const float*)d_in[9];
    const float* fmk_w2 = (const float*)d_in[10];
    const float* fmk_b2 = (const float*)d_in[11];
    const float* rms_w  = (const float*)d_in[12];
    const float* Wo     = (const float*)d_in[13];
    const float* Wp     = (const float*)d_in[14];
    const float* bp     = (const float*)d_in[15];
    float* out = (float*)d_out;

    const long nTD = (long)NB * TSEQ * DD;
    _Float16* qf  = (_Float16*)d_ws;
    _Float16* Wh  = qf + nTD;                    // 6 fp16 matrices
    float* STf    = (float*)(Wh + 6 * DD * DD);
    _Float16* STh = (_Float16*)(STf + (long)NB * K2_SPLIT * DD * DD);
    float* pooled = (float*)(STh + NB * DD * DD);

    k0_prep<<<(2 * DD * DD) / 256, 256, 0, stream>>>(Wv, Wo, rms_w, Wh, pooled);
    k0_fold<<<32, 256, 0, stream>>>(Wq, Wk, fmq_w1, fmq_w2, fmk_w1, fmk_w2, Wh);
    k1_mega<<<(NB * TSEQ) / (K1_TM * K1_G), 512, 0, stream>>>(
        x, Wh, fmq_b1, fmq_b2, fmk_b1, fmk_b2, qf, STf);
    k2r_reduce<<<(NB * DD * DD) / 256, 256, 0, stream>>>(STf, STh);
    k3_ostage<<<(NB * TSEQ) / K3_TC, 512, 0, stream>>>(qf, STh, Wh + 5 * DD * DD, pooled);
    k4_final<<<NB, HH, 0, stream>>>(pooled, Wp, bp, out);
}

// Round 3
// 393.800 us; speedup vs baseline: 1.2448x; 1.1985x over previous
//
#include <hip/hip_runtime.h>
#include <math.h>

#define NB   16
#define TSEQ 16384
#define DD   128
#define HH   256
constexpr float EPS = 1e-5f;

typedef _Float16 h8v __attribute__((ext_vector_type(8)));
typedef _Float16 h4v __attribute__((ext_vector_type(4)));
typedef float    f4v __attribute__((ext_vector_type(4)));

#define MFMA16(a, b, c) __builtin_amdgcn_mfma_f32_16x16x32_f16(a, b, c, 0, 0, 0)

constexpr int SX_S = 136;   // 272B rows: 2-way bank alias on b128 (free)
constexpr int SW_S = 136;
constexpr int K1_TM = 128;  // rows per tile
constexpr int K1_G  = 4;    // tiles per k1 block (split-K depth 512 t)
constexpr int K2_SPLIT = 32;  // partial S slots per batch = 512 blocks / 16 batches

__device__ __forceinline__ void atomicMaxFloat(float* addr, float val) {
    if (val >= 0.0f) atomicMax((int*)addr, __float_as_int(val));
    else             atomicMin((unsigned int*)addr, __float_as_uint(val));
}

// ---------------------------------------------------------------------------
// K0: cast Wv -> Wh[4], Wo*rms_w -> Wh[5]; init pooled.
// ---------------------------------------------------------------------------
__global__ __launch_bounds__(256) void k0_prep(
    const float* __restrict__ Wv, const float* __restrict__ Wo,
    const float* __restrict__ rmsw,
    _Float16* __restrict__ Wh, float* __restrict__ pooled)
{
    const int i = blockIdx.x * 256 + threadIdx.x;
    if (i < 2 * DD * DD) {
        const int mat = i >> 14;
        const int e   = i & (DD * DD - 1);
        float v = (mat == 0) ? Wv[e] : Wo[e] * rmsw[e & (DD - 1)];
        Wh[(4 + mat) * DD * DD + e] = (_Float16)v;
    }
    if (i < NB * DD) pooled[i] = -INFINITY;
}

// ---------------------------------------------------------------------------
// K0b: fold feature-map weights through the projections:
//   Wh[0]=fmq_w1@Wq  Wh[1]=fmq_w2@Wq  Wh[2]=fmk_w1@Wk  Wh[3]=fmk_w2@Wk
// ---------------------------------------------------------------------------
__global__ __launch_bounds__(256) void k0_fold(
    const float* __restrict__ Wq, const float* __restrict__ Wk,
    const float* __restrict__ fq1, const float* __restrict__ fq2,
    const float* __restrict__ fk1, const float* __restrict__ fk2,
    _Float16* __restrict__ Wh)
{
    __shared__ _Float16 sW[DD * SX_S];   // base matrix [o][i]
    __shared__ _Float16 sF[16 * SX_S];   // fm rows     [o2r][o]
    const int mat  = blockIdx.x >> 3;    // 0..3
    const int rblk = blockIdx.x & 7;     // 16-row slice
    const float* fms[4] = {fq1, fq2, fk1, fk2};
    const float* base = (mat < 2) ? Wq : Wk;
    const float* fm   = fms[mat];
    const int tid = threadIdx.x;
    {   // stage base [128][128] fp32->fp16
        const int r = tid >> 1, c0 = (tid & 1) * 64;
        const float* src = base + r * DD + c0;
        _Float16* dst = sW + r * SX_S + c0;
#pragma unroll
        for (int i = 0; i < 16; ++i) {
            const float4 v = *(const float4*)(src + i * 4);
            h4v h; h[0] = (_Float16)v.x; h[1] = (_Float16)v.y;
                   h[2] = (_Float16)v.z; h[3] = (_Float16)v.w;
            *(h4v*)(dst + i * 4) = h;
        }
    }
    {   // stage fm rows [rblk*16 .. +16)
        const int r = tid >> 4, c0 = (tid & 15) * 8;
        const float* src = fm + (rblk * 16 + r) * DD + c0;
        _Float16* dst = sF + r * SX_S + c0;
#pragma unroll
        for (int i = 0; i < 2; ++i) {
            const float4 v = *(const float4*)(src + i * 4);
            h4v h; h[0] = (_Float16)v.x; h[1] = (_Float16)v.y;
                   h[2] = (_Float16)v.z; h[3] = (_Float16)v.w;
            *(h4v*)(dst + i * 4) = h;
        }
    }
    __syncthreads();
    const int o2r = tid >> 4, i0 = (tid & 15) * 8;
    float acc[8] = {0.f, 0.f, 0.f, 0.f, 0.f, 0.f, 0.f, 0.f};
    for (int o = 0; o < DD; ++o) {
        const float f = (float)sF[o2r * SX_S + o];
        const h8v w8 = *(const h8v*)(sW + o * SX_S + i0);
#pragma unroll
        for (int j = 0; j < 8; ++j) acc[j] = fmaf(f, (float)w8[j], acc[j]);
    }
    h8v hv;
#pragma unroll
    for (int j = 0; j < 8; ++j) hv[j] = (_Float16)acc[j];
    *(h8v*)(Wh + mat * DD * DD + (rblk * 16 + o2r) * DD + i0) = hv;
}

// ---------------------------------------------------------------------------
// K1-mega v3: 1024 threads / 16 waves, spill-free register budget.
// Wave wv: n-tile nt8 = wv&7 (output cols / d), m-half mh = wv>>3 (rows).
// Per GEMM each wave computes 4 fragments (a1[4]); loop-carried accS[4].
// Peak regs ~ accS(16)+a1(16)+w(16)+t(4)+misc(~25) ~ 90 < 128 cap (1024,4).
// per 128-t tile (G=4 tiles/block):
//   qf = (x@A1q^T+b1)*(x@A2q^T+b2) -> global [t][d]
//   kf = (x@A1k^T+b1)*(x@A2k^T+b2) -> LDS [d][t]
//   v  = x@Wv^T                    -> LDS [e][t]
//   accS[e][d] += v^T x kf^T       (split-K partial of S^T)
// ---------------------------------------------------------------------------
__global__ __launch_bounds__(1024, 4) void k1_mega(
    const float* __restrict__ x, const _Float16* __restrict__ Wh,
    const float* __restrict__ bq1, const float* __restrict__ bq2,
    const float* __restrict__ bk1, const float* __restrict__ bk2,
    _Float16* __restrict__ qf, float* __restrict__ STf)
{
    __shared__ _Float16 sX[K1_TM * SX_S];    // x tile [t][d], later v^T [e][t]
    __shared__ _Float16 sCT[K1_TM * SX_S];   // qf [t][d], later kf^T [d][t]

    const int tid = threadIdx.x;
    const int wv = tid >> 6;                 // 0..15
    const int nt8 = wv & 7;                  // n-tile (output cols)
    const int mh  = wv >> 3;                 // m-half (0/1)
    const int ln = tid & 63, lm = ln & 15, lq = ln >> 4;
    const long tb = (long)blockIdx.x * (K1_TM * K1_G);
    const int b = (int)(tb >> 14);

    const float vb1q = bq1[nt8 * 16 + lm], vb2q = bq2[nt8 * 16 + lm];
    const float vb1k = bk1[nt8 * 16 + lm], vb2k = bk2[nt8 * 16 + lm];

    auto loadW = [&](int mat, h8v* w) {
        const _Float16* p = Wh + mat * DD * DD + (nt8 * 16 + lm) * DD + lq * 8;
#pragma unroll
        for (int k0 = 0; k0 < 4; ++k0) w[k0] = *(const h8v*)(p + k0 * 32);
    };
    auto gemm = [&](const _Float16* sA, const h8v* w, f4v* acc) {
#pragma unroll
        for (int k0 = 0; k0 < 4; ++k0)
#pragma unroll
            for (int mt = 0; mt < 4; ++mt) {
                const h8v a = *(const h8v*)(sA + ((mh * 4 + mt) * 16 + lm) * SX_S + k0 * 32 + lq * 8);
                acc[mt] = MFMA16(a, w[k0], acc[mt]);
            }
    };
    // second GEMM fused: per-mt fragment t, hadamard into a immediately
    auto fusedHad = [&](const _Float16* sA, const h8v* w, f4v* a,
                        float b1, float b2) {
#pragma unroll
        for (int mt = 0; mt < 4; ++mt) {
            f4v t; t[0] = 0.f; t[1] = 0.f; t[2] = 0.f; t[3] = 0.f;
#pragma unroll
            for (int k0 = 0; k0 < 4; ++k0) {
                const h8v av = *(const h8v*)(sA + ((mh * 4 + mt) * 16 + lm) * SX_S + k0 * 32 + lq * 8);
                t = MFMA16(av, w[k0], t);
            }
#pragma unroll
            for (int r = 0; r < 4; ++r)
                a[mt][r] = (a[mt][r] + b1) * (t[r] + b2);
        }
    };
    auto zero4 = [&](f4v* a) {
#pragma unroll
        for (int i = 0; i < 4; ++i) { a[i][0] = 0.f; a[i][1] = 0.f; a[i][2] = 0.f; a[i][3] = 0.f; }
    };
    auto cToC = [&](const f4v* a) {          // a -> sCT [t][d]
#pragma unroll
        for (int mt = 0; mt < 4; ++mt)
#pragma unroll
            for (int r = 0; r < 4; ++r)
                sCT[((mh * 4 + mt) * 16 + lq * 4 + r) * SX_S + nt8 * 16 + lm] = (_Float16)a[mt][r];
    };
    auto cToT = [&](const f4v* a, _Float16* dst) {  // a -> dst [d][t]
#pragma unroll
        for (int mt = 0; mt < 4; ++mt) {
            h4v h;
#pragma unroll
            for (int r = 0; r < 4; ++r) h[r] = (_Float16)a[mt][r];
            *(h4v*)(dst + (nt8 * 16 + lm) * SX_S + (mh * 4 + mt) * 16 + lq * 4) = h;
        }
    };

    f4v accS[4];
    zero4(accS);

    h8v w[4];
    f4v a1[4];

#pragma unroll 1
    for (int g = 0; g < K1_G; ++g) {
        const long t0 = tb + (long)g * K1_TM;

        {   // stage x [128][128] fp32->fp16 (1024 thr: 16 elems each)
            const int r = tid >> 3, c0 = (tid & 7) * 16;
            const float* src = x + (t0 + r) * DD + c0;
            _Float16* dst = sX + r * SX_S + c0;
#pragma unroll
            for (int i = 0; i < 4; ++i) {
                const float4 v = *(const float4*)(src + i * 4);
                h4v h; h[0] = (_Float16)v.x; h[1] = (_Float16)v.y;
                       h[2] = (_Float16)v.z; h[3] = (_Float16)v.w;
                *(h4v*)(dst + i * 4) = h;
            }
        }
        __syncthreads();                       // B1: sX ready (B6 guarded prev reads)

        // ---------------- q
        loadW(0, w);
        zero4(a1); gemm(sX, w, a1);            // qa
        loadW(1, w);
        fusedHad(sX, w, a1, vb1q, vb2q);       // a1 = (qa+b1)*(qb+b2)
        cToC(a1);                              // qf -> sCT [t][d]
        __syncthreads();                       // B2: sCT = qf
        {   // qf -> global [t][d] (16 halfs/thread)
            const int r = tid >> 3, c0 = (tid & 7) * 16;
            const _Float16* s = sCT + r * SX_S + c0;
            _Float16* d = qf + (t0 + r) * DD + c0;
            *(h8v*)(d)     = *(const h8v*)(s);
            *(h8v*)(d + 8) = *(const h8v*)(s + 8);
        }

        // ---------------- k (reads sX only; overlaps qf store latency)
        loadW(2, w);
        zero4(a1); gemm(sX, w, a1);            // ka
        loadW(3, w);
        fusedHad(sX, w, a1, vb1k, vb2k);       // a1 = kf (fp32)
        __syncthreads();                       // B3: qf copy reads of sCT done
        cToT(a1, sCT);                         // kf^T -> sCT [d][t]

        // ---------------- v (reads sX; sCT writes in flight, no conflict)
        loadW(4, w);
        zero4(a1); gemm(sX, w, a1);            // v
        __syncthreads();                       // B4: all sX reads + kf^T writes done
        cToT(a1, sX);                          // v^T -> sX [e][t]
        __syncthreads();                       // B5: transposes ready

        // ---------------- S partial: accS[m=e][n=d] += v^T x kf^T over t(128)
#pragma unroll
        for (int k0 = 0; k0 < 4; ++k0) {
            const h8v bk = *(const h8v*)(sCT + (nt8 * 16 + lm) * SX_S + k0 * 32 + lq * 8);
#pragma unroll
            for (int mt = 0; mt < 4; ++mt) {
                const h8v av = *(const h8v*)(sX + ((mh * 4 + mt) * 16 + lm) * SX_S + k0 * 32 + lq * 8);
                accS[mt] = MFMA16(av, bk, accS[mt]);
            }
        }
        __syncthreads();                       // B6: S reads done before next stage
    }

    // write split-K partial S^T [e][d] (same layout/slots as old K2)
    float* Pb = STf + (long)(b * K2_SPLIT + (blockIdx.x & (K2_SPLIT - 1))) * (DD * DD);
#pragma unroll
    for (int mt = 0; mt < 4; ++mt)
#pragma unroll
        for (int r = 0; r < 4; ++r)
            Pb[((mh * 4 + mt) * 16 + lq * 4 + r) * DD + nt8 * 16 + lm] = accS[mt][r];
}

// ---------------------------------------------------------------------------
// K2r: sum the 32 split-K partials per batch -> fp16 S^T. (unchanged)
// ---------------------------------------------------------------------------
__global__ __launch_bounds__(256) void k2r_reduce(const float* __restrict__ STf,
                                                  _Float16* __restrict__ STh)
{
    const int idx = blockIdx.x * 256 + threadIdx.x;
    const int b = idx >> 14, e = idx & (DD * DD - 1);
    const float* p = STf + (long)b * K2_SPLIT * (DD * DD) + e;
    float s0 = 0.f, s1 = 0.f, s2 = 0.f, s3 = 0.f;
#pragma unroll
    for (int j = 0; j < K2_SPLIT; j += 4) {
        s0 += p[(long)(j + 0) * (DD * DD)];
        s1 += p[(long)(j + 1) * (DD * DD)];
        s2 += p[(long)(j + 2) * (DD * DD)];
        s3 += p[(long)(j + 3) * (DD * DD)];
    }
    STh[idx] = (_Float16)((s0 + s1) + (s2 + s3));
}

// ---------------------------------------------------------------------------
// K3 (unchanged; Wo' lives at Wh[5]).
// ---------------------------------------------------------------------------
constexpr int K3_TC = 128;

__global__ __launch_bounds__(512, 4) void k3_ostage(const _Float16* __restrict__ qf,
                                                    const _Float16* __restrict__ STh,
                                                    const _Float16* __restrict__ WoH,
                                                    float* __restrict__ pooled)
{
    __shared__ _Float16 sA[DD * SW_S];
    __shared__ _Float16 sB[K3_TC * SX_S];
    __shared__ float sPart[2][DD];
    __shared__ float sRed[8][DD];
    const int tid = threadIdx.x;
    const int wv = tid >> 6, ln = tid & 63, lm = ln & 15, lq = ln >> 4;
    const int eg = wv & 1;
    const int tg = wv >> 1;
    const long t0 = (long)blockIdx.x * K3_TC;
    const int b = (int)(t0 >> 14);

    h8v wo[4];
    {
        const int r = tid >> 2, c0 = (tid & 3) * 32;
        const _Float16* src = WoH + r * DD + c0;
        wo[0] = *(const h8v*)(src);
        wo[1] = *(const h8v*)(src + 8);
        wo[2] = *(const h8v*)(src + 16);
        wo[3] = *(const h8v*)(src + 24);
    }
    {
        const int r = tid >> 2, c0 = (tid & 3) * 32;
        const _Float16* src = STh + (long)b * DD * DD + r * DD + c0;
        _Float16* dst = sA + r * SW_S + c0;
        *(h8v*)(dst)      = *(const h8v*)(src);
        *(h8v*)(dst + 8)  = *(const h8v*)(src + 8);
        *(h8v*)(dst + 16) = *(const h8v*)(src + 16);
        *(h8v*)(dst + 24) = *(const h8v*)(src + 24);
    }
    {
        const int r = tid >> 2, c0 = (tid & 3) * 32;
        const _Float16* src = qf + (t0 + r) * DD + c0;
        _Float16* dst = sB + r * SX_S + c0;
        *(h8v*)(dst)      = *(const h8v*)(src);
        *(h8v*)(dst + 8)  = *(const h8v*)(src + 8);
        *(h8v*)(dst + 16) = *(const h8v*)(src + 16);
        *(h8v*)(dst + 24) = *(const h8v*)(src + 24);
    }
    __syncthreads();                        // B1

    f4v acc[2][4];
#pragma unroll
    for (int i = 0; i < 2; ++i)
#pragma unroll
        for (int j = 0; j < 4; ++j) { acc[i][j][0]=0.f; acc[i][j][1]=0.f; acc[i][j][2]=0.f; acc[i][j][3]=0.f; }
#pragma unroll
    for (int k0 = 0; k0 < 4; ++k0) {
        const h8v bf0 = *(const h8v*)(sB + ((tg * 2 + 0) * 16 + lm) * SX_S + k0 * 32 + lq * 8);
        const h8v bf1 = *(const h8v*)(sB + ((tg * 2 + 1) * 16 + lm) * SX_S + k0 * 32 + lq * 8);
#pragma unroll
        for (int a = 0; a < 4; ++a) {
            const h8v af = *(const h8v*)(sA + ((eg * 4 + a) * 16 + lm) * SW_S + k0 * 32 + lq * 8);
            acc[0][a] = MFMA16(af, bf0, acc[0][a]);
            acc[1][a] = MFMA16(af, bf1, acc[1][a]);
        }
    }
    float ssp[2] = {0.f, 0.f};
#pragma unroll
    for (int bt = 0; bt < 2; ++bt)
#pragma unroll
        for (int a = 0; a < 4; ++a)
#pragma unroll
            for (int r = 0; r < 4; ++r) ssp[bt] += acc[bt][a][r] * acc[bt][a][r];
#pragma unroll
    for (int bt = 0; bt < 2; ++bt) {
        ssp[bt] += __shfl_xor(ssp[bt], 16, 64);
        ssp[bt] += __shfl_xor(ssp[bt], 32, 64);
    }
    if (lq == 0) {
        sPart[eg][tg * 32 + 0 * 16 + lm] = ssp[0];
        sPart[eg][tg * 32 + 1 * 16 + lm] = ssp[1];
    }
    __syncthreads();                        // B2
    float sc[2];
#pragma unroll
    for (int bt = 0; bt < 2; ++bt) {
        const int t = tg * 32 + bt * 16 + lm;
        sc[bt] = rsqrtf((sPart[0][t] + sPart[1][t]) * (1.0f / DD) + EPS);
    }
#pragma unroll
    for (int bt = 0; bt < 2; ++bt)
#pragma unroll
        for (int a = 0; a < 4; ++a) {
            h4v h;
#pragma unroll
            for (int r = 0; r < 4; ++r) h[r] = (_Float16)(acc[bt][a][r] * sc[bt]);
            *(h4v*)(sB + ((tg * 2 + bt) * 16 + lm) * SX_S + (eg * 4 + a) * 16 + lq * 4) = h;
        }
    {
        const int r = tid >> 2, c0 = (tid & 3) * 32;
        _Float16* dst = sA + r * SW_S + c0;
        *(h8v*)(dst)      = wo[0];
        *(h8v*)(dst + 8)  = wo[1];
        *(h8v*)(dst + 16) = wo[2];
        *(h8v*)(dst + 24) = wo[3];
    }
    __syncthreads();                        // B3

#pragma unroll
    for (int i = 0; i < 2; ++i)
#pragma unroll
        for (int j = 0; j < 4; ++j) { acc[i][j][0]=0.f; acc[i][j][1]=0.f; acc[i][j][2]=0.f; acc[i][j][3]=0.f; }
#pragma unroll
    for (int k0 = 0; k0 < 4; ++k0) {
        const h8v bf0 = *(const h8v*)(sB + ((tg * 2 + 0) * 16 + lm) * SX_S + k0 * 32 + lq * 8);
        const h8v bf1 = *(const h8v*)(sB + ((tg * 2 + 1) * 16 + lm) * SX_S + k0 * 32 + lq * 8);
#pragma unroll
        for (int a = 0; a < 4; ++a) {
            const h8v af = *(const h8v*)(sA + ((eg * 4 + a) * 16 + lm) * SW_S + k0 * 32 + lq * 8);
            acc[0][a] = MFMA16(af, bf0, acc[0][a]);
            acc[1][a] = MFMA16(af, bf1, acc[1][a]);
        }
    }
#pragma unroll
    for (int a = 0; a < 4; ++a)
#pragma unroll
        for (int r = 0; r < 4; ++r) {
            float m = fmaxf(acc[0][a][r], acc[1][a][r]);
            m = fmaxf(m, __shfl_xor(m, 1, 64));
            m = fmaxf(m, __shfl_xor(m, 2, 64));
            m = fmaxf(m, __shfl_xor(m, 4, 64));
            m = fmaxf(m, __shfl_xor(m, 8, 64));
            if (lm == 0) sRed[wv][(eg * 4 + a) * 16 + lq * 4 + r] = m;
        }
    __syncthreads();                        // B4
    if (tid < DD) {
        const int egc = tid >> 6;
        float m = sRed[0 * 2 + egc][tid];
#pragma unroll
        for (int g = 1; g < 4; ++g) m = fmaxf(m, sRed[g * 2 + egc][tid]);
        atomicMaxFloat(&pooled[b * DD + tid], m);
    }
}

// ---------------------------------------------------------------------------
// K4: out[b,h] = pooled[b] . Wp[h] + bp[h]
// ---------------------------------------------------------------------------
__global__ __launch_bounds__(HH) void k4_final(const float* __restrict__ pooled,
                                               const float* __restrict__ Wp,
                                               const float* __restrict__ bp,
                                               float* __restrict__ out)
{
    const int b = blockIdx.x;
    const int h = threadIdx.x;
    __shared__ float sp[DD];
    if (h < DD) sp[h] = pooled[b * DD + h];
    __syncthreads();
    float acc = bp[h];
#pragma unroll 8
    for (int d = 0; d < DD; ++d) acc = fmaf(sp[d], Wp[(long)h * DD + d], acc);
    out[b * HH + h] = acc;
}

// ---------------------------------------------------------------------------
extern "C" void kernel_launch(void* const* d_in, const int* in_sizes, int n_in,
                              void* d_out, int out_size, void* d_ws, size_t ws_size,
                              hipStream_t stream)
{
    const float* x      = (const float*)d_in[0];
    const float* Wq     = (const float*)d_in[1];
    const float* Wk     = (const float*)d_in[2];
    const float* Wv     = (const float*)d_in[3];
    const float* fmq_w1 = (const float*)d_in[4];
    const float* fmq_b1 = (const float*)d_in[5];
    const float* fmq_w2 = (const float*)d_in[6];
    const float* fmq_b2 = (const float*)d_in[7];
    const float* fmk_w1 = (const float*)d_in[8];
    const float* fmk_b1 = (const float*)d_in[9];
    const float* fmk_w2 = (const float*)d_in[10];
    const float* fmk_b2 = (const float*)d_in[11];
    const float* rms_w  = (const float*)d_in[12];
    const float* Wo     = (const float*)d_in[13];
    const float* Wp     = (const float*)d_in[14];
    const float* bp     = (const float*)d_in[15];
    float* out = (float*)d_out;

    const long nTD = (long)NB * TSEQ * DD;
    _Float16* qf  = (_Float16*)d_ws;
    _Float16* Wh  = qf + nTD;                    // 6 fp16 matrices
    float* STf    = (float*)(Wh + 6 * DD * DD);
    _Float16* STh = (_Float16*)(STf + (long)NB * K2_SPLIT * DD * DD);
    float* pooled = (float*)(STh + NB * DD * DD);

    k0_prep<<<(2 * DD * DD) / 256, 256, 0, stream>>>(Wv, Wo, rms_w, Wh, pooled);
    k0_fold<<<32, 256, 0, stream>>>(Wq, Wk, fmq_w1, fmq_w2, fmk_w1, fmk_w2, Wh);
    k1_mega<<<(NB * TSEQ) / (K1_TM * K1_G), 1024, 0, stream>>>(
        x, Wh, fmq_b1, fmq_b2, fmk_b1, fmk_b2, qf, STf);
    k2r_reduce<<<(NB * DD * DD) / 256, 256, 0, stream>>>(STf, STh);
    k3_ostage<<<(NB * TSEQ) / K3_TC, 512, 0, stream>>>(qf, STh, Wh + 5 * DD * DD, pooled);
    k4_final<<<NB, HH, 0, stream>>>(pooled, Wp, bp, out);
}